// Round 10
// baseline (246.276 us; speedup 1.0000x reference)
//
#include <hip/hip_runtime.h>
#include <hip/hip_bf16.h>

// B=4, N=128, L=20, D=512
#define Bc 4
#define Nc 128
#define Lc 20
#define Dc 512
#define SCALE 0.04419417382415922f   // 1/sqrt(512)
#define NL2E -1.4426950408889634f    // -log2(e)

#if __has_builtin(__builtin_amdgcn_exp2f)
#define EXP2(x) __builtin_amdgcn_exp2f(x)
#else
#define EXP2(x) __expf((x) * 0.6931471805599453f)
#endif

// ---------------------------------------------------------------------------
// Kernel 1: q/k projections. 32x32 tiles, 2x2 micro-tile, k-major LDS,
// register prefetch. K-split: q 8-way (K=64 each, 2048 blocks),
// k 2-way (K=256 each, 96 blocks). 2144 blocks ~ 8.4/CU.
// Partial outputs; consumers sum parts.
// ---------------------------------------------------------------------------
__global__ __launch_bounds__(256)
void proj_gemm(const float* __restrict__ f_b, const float* __restrict__ f_w,
               const float* __restrict__ Wq, const float* __restrict__ bq,
               const float* __restrict__ Wk, const float* __restrict__ bk,
               float* __restrict__ qb, float* __restrict__ kb) {
    const int t   = threadIdx.x;
    const int idx = blockIdx.x;
    const bool isq = idx < 2048;
    int kh, tr, tc, KS;
    if (isq) { kh = idx >> 8; const int r = idx & 255; tr = r >> 4; tc = r & 15; KS = 64; }
    else     { const int r = idx - 2048; kh = r / 48; const int r3 = r % 48;
               tr = r3 / 16; tc = r3 % 16; KS = 256; }

    const int c0 = tc * 32;
    const float* Ain  = isq ? f_b : f_w;
    const float* W    = isq ? Wq : Wk;
    const float* bias = isq ? bq : bk;           // added only in kh==0 part
    float* C          = isq ? (qb + kh * 512 * Dc) : (kb + kh * 80 * Dc);
    const int r0    = tr * 32;
    const int nrows = isq ? 512 : 80;
    const int kbase = kh * KS;

    __shared__ __align__(16) float As[16 * 34];   // [k][row+pad]
    __shared__ __align__(16) float Bs[16 * 34];

    const int sr  = t >> 3;            // staged row 0..31
    const int sk2 = (t & 7) * 2;       // staged k pair 0..14
    const int arow = min(r0 + sr, nrows - 1);
    const int wrow = c0 + sr;

    const int ty2 = (t >> 4) * 2;      // out row pair
    const int tx2 = (t & 15) * 2;      // out col pair
    float a00 = 0.f, a01 = 0.f, a10 = 0.f, a11 = 0.f;

    const float* Aptr = Ain + arow * Dc + kbase + sk2;
    const float* Wptr = W   + wrow * Dc + kbase + sk2;
    float2 ga = *(const float2*)Aptr;
    float2 gb = *(const float2*)Wptr;

    for (int kk0 = 16; kk0 <= KS; kk0 += 16) {
        __syncthreads();
        As[sk2 * 34 + sr]       = ga.x;
        As[(sk2 + 1) * 34 + sr] = ga.y;
        Bs[sk2 * 34 + sr]       = gb.x;
        Bs[(sk2 + 1) * 34 + sr] = gb.y;
        __syncthreads();
        if (kk0 < KS) {                       // prefetch next tile
            ga = *(const float2*)(Aptr + kk0);
            gb = *(const float2*)(Wptr + kk0);
        }
#pragma unroll
        for (int kk = 0; kk < 16; kk++) {
            const float2 av = *(const float2*)&As[kk * 34 + ty2];
            const float2 bv = *(const float2*)&Bs[kk * 34 + tx2];
            a00 = fmaf(av.x, bv.x, a00); a01 = fmaf(av.x, bv.y, a01);
            a10 = fmaf(av.y, bv.x, a10); a11 = fmaf(av.y, bv.y, a11);
        }
    }
    const int orow = r0 + ty2;
    const float b0 = kh ? 0.f : bias[c0 + tx2];
    const float b1 = kh ? 0.f : bias[c0 + tx2 + 1];
    if (orow < nrows)
        *(float2*)&C[orow * Dc + c0 + tx2] = make_float2(a00 + b0, a01 + b1);
    if (orow + 1 < nrows)
        *(float2*)&C[(orow + 1) * Dc + c0 + tx2] = make_float2(a10 + b0, a11 + b1);
}

// ---------------------------------------------------------------------------
// Kernel 2: cross-attention over L=20 + sentence gate -> f_bq
// 512 threads (8 waves -> 4 waves/SIMD). Sums 8 q-parts, 2 k-parts.
// ---------------------------------------------------------------------------
__global__ __launch_bounds__(512)
void cross_attn_gate(const float* __restrict__ qb, const float* __restrict__ kb,
                     const float* __restrict__ f_w, const float* __restrict__ f_b,
                     const float* __restrict__ f_s, float* __restrict__ f_bq) {
    const int bn = blockIdx.x;
    const int b  = bn >> 7;
    const int t  = threadIdx.x;          // 0..511
    const int lane = t & 63, wave = t >> 6;   // 8 waves

    __shared__ __align__(16) float qs[Dc];
    __shared__ float sc[32];
    __shared__ float invs;

    {
        float s = 0.f;
#pragma unroll
        for (int h = 0; h < 8; h++) s += qb[h * 512 * Dc + bn * Dc + t];
        qs[t] = s;
    }
    __syncthreads();

    const float4* q4 = (const float4*)qs;
    const float4 qa = q4[lane];
    const float4 qv = q4[lane + 64];

    for (int l = wave; l < Lc; l += 8) {
        const float4* kr0 = (const float4*)(kb + (b * Lc + l) * Dc);
        const float4* kr1 = (const float4*)(kb + 80 * Dc + (b * Lc + l) * Dc);
        const float4 u0 = kr0[lane],      u1 = kr1[lane];
        const float4 v0 = kr0[lane + 64], v1 = kr1[lane + 64];
        const float4 ka = make_float4(u0.x + u1.x, u0.y + u1.y, u0.z + u1.z, u0.w + u1.w);
        const float4 kv = make_float4(v0.x + v1.x, v0.y + v1.y, v0.z + v1.z, v0.w + v1.w);
        float s = qa.x * ka.x + qa.y * ka.y + qa.z * ka.z + qa.w * ka.w
                + qv.x * kv.x + qv.y * kv.y + qv.z * kv.z + qv.w * kv.w;
#pragma unroll
        for (int d = 32; d >= 1; d >>= 1) s += __shfl_down(s, d, 64);
        if (lane == 0) sc[l] = s * SCALE;
    }
    __syncthreads();

    if (t == 0) {
        float mx = sc[0];
        for (int l = 1; l < Lc; l++) mx = fmaxf(mx, sc[l]);
        float sum = 0.f;
        for (int l = 0; l < Lc; l++) { float e = __expf(sc[l] - mx); sc[l] = e; sum += e; }
        invs = 1.0f / sum;
    }
    __syncthreads();
    const float inv = invs;

    const float* fw = f_w + b * Lc * Dc;
    float acc = 0.f;
#pragma unroll 5
    for (int l = 0; l < Lc; l++) acc = fmaf(sc[l], fw[l * Dc + t], acc);
    f_bq[bn * Dc + t] = f_b[bn * Dc + t] * (acc * inv + f_s[b * Dc + t]);
}

// ---------------------------------------------------------------------------
// Kernel 3: A_b / A_bT softmax rows. 512 threads (8 waves -> 4 waves/SIMD).
// ---------------------------------------------------------------------------
__global__ __launch_bounds__(512)
void self_attn_scores(const float* __restrict__ f_bq,
                      float* __restrict__ A_b, float* __restrict__ A_bT) {
    const int bn = blockIdx.x;
    const int b  = bn >> 7, n = bn & 127;
    const int t  = threadIdx.x;          // 0..511
    const int lane = t & 63, wave = t >> 6;   // 8 waves

    __shared__ __align__(16) float qrow[Dc];
    __shared__ float sc[Nc];
    __shared__ float red[Nc];

    qrow[t] = f_bq[bn * Dc + t];
    __syncthreads();

    const float4* q4 = (const float4*)qrow;
    const float4 qa = q4[lane];
    const float4 qv = q4[lane + 64];

    for (int m = wave; m < Nc; m += 8) {
        const float4* kr = (const float4*)(f_bq + (b * Nc + m) * Dc);
        const float4 va = kr[lane];
        const float4 vb = kr[lane + 64];
        float s = qa.x * va.x + qa.y * va.y + qa.z * va.z + qa.w * va.w
                + qv.x * vb.x + qv.y * vb.y + qv.z * vb.z + qv.w * vb.w;
#pragma unroll
        for (int d = 32; d >= 1; d >>= 1) s += __shfl_down(s, d, 64);
        if (lane == 0) sc[m] = s * SCALE;
    }
    __syncthreads();

    float e = 0.f, sval = 0.f;
    if (t < Nc) { sval = sc[t]; red[t] = sval; }
    __syncthreads();
    for (int st = 64; st >= 1; st >>= 1) {
        if (t < st) red[t] = fmaxf(red[t], red[t + st]);
        __syncthreads();
    }
    const float mx = red[0];
    __syncthreads();
    if (t < Nc) { e = __expf(sval - mx); red[t] = e; }
    __syncthreads();
    for (int st = 64; st >= 1; st >>= 1) {
        if (t < st) red[t] += red[t + st];
        __syncthreads();
    }
    if (t < Nc) {
        const float a = e * (1.0f / red[0]);
        A_b[bn * Nc + t] = a;
        A_bT[(b * Nc + t) * Nc + n] = a;
    }
}

// ---------------------------------------------------------------------------
// Kernel 4: fused moment reduction + self-attn apply + residual.
// grid (512, 4): blockIdx.x = (b,j), blockIdx.y = d-quarter (32 float4).
// 256 threads = 32 f4-lanes x 8 i/m-groups -> 2048 blocks = 8 blocks/CU.
// ---------------------------------------------------------------------------
__global__ __launch_bounds__(256, 8)
void moment_final(const float* __restrict__ f_m, const float* __restrict__ f_s,
                  const float* __restrict__ A_b, const float* __restrict__ A_bT,
                  const float* __restrict__ f_b, float* __restrict__ out) {
    const int bj = blockIdx.x;
    const int b  = bj >> 7, j = bj & 127;
    const int dq = blockIdx.y;         // 0..3
    const int t  = threadIdx.x;        // 0..255
    const int c  = t & 31;             // f4 lane within d-quarter
    const int g  = t >> 5;             // 0..7 i/m group

    __shared__ float w[Nc];
    __shared__ float ar[Nc];
    __shared__ __align__(16) float4 pex[7][32];

    if (t < Nc) w[t] = A_bT[bj * Nc + t];
    else        ar[t - Nc] = A_b[bj * Nc + (t - Nc)];
    __syncthreads();

    const int c4 = dq * 32 + c;        // global f4 column 0..127
    const float4 s4 = ((const float4*)(f_s + b * Dc))[c4];
    const float4 ns = make_float4(NL2E * s4.x, NL2E * s4.y, NL2E * s4.z, NL2E * s4.w);

    float4 acc = make_float4(0.f, 0.f, 0.f, 0.f);
    const float4* fm4 = (const float4*)f_m;
    int idx = ((b * Nc + g * 16) * Nc + j) * (Dc / 4) + c4;   // i-stride = 128*128 f4

#pragma unroll 4
    for (int i = 0; i < 16; i++) {
        const float4 m4 = fm4[idx];
        idx += Nc * (Dc / 4);
        const float ww = w[g * 16 + i];
        acc.x = fmaf(ww * m4.x, __builtin_amdgcn_rcpf(1.f + EXP2(m4.x * ns.x)), acc.x);
        acc.y = fmaf(ww * m4.y, __builtin_amdgcn_rcpf(1.f + EXP2(m4.y * ns.y)), acc.y);
        acc.z = fmaf(ww * m4.z, __builtin_amdgcn_rcpf(1.f + EXP2(m4.z * ns.z)), acc.z);
        acc.w = fmaf(ww * m4.w, __builtin_amdgcn_rcpf(1.f + EXP2(m4.w * ns.w)), acc.w);
    }

    const float4* fb4 = (const float4*)(f_b + b * Nc * Dc);
#pragma unroll 4
    for (int m = g * 16; m < g * 16 + 16; m++) {
        const float a = ar[m];
        const float4 v = fb4[m * (Dc / 4) + c4];
        acc.x = fmaf(a, v.x, acc.x); acc.y = fmaf(a, v.y, acc.y);
        acc.z = fmaf(a, v.z, acc.z); acc.w = fmaf(a, v.w, acc.w);
    }

    if (g != 0) pex[g - 1][c] = acc;
    __syncthreads();
    if (g == 0) {
#pragma unroll
        for (int p = 0; p < 7; p++) {
            const float4 q = pex[p][c];
            acc.x += q.x; acc.y += q.y; acc.z += q.z; acc.w += q.w;
        }
        const float4 r = fb4[j * (Dc / 4) + c4];   // residual
        acc.x += r.x; acc.y += r.y; acc.z += r.z; acc.w += r.w;
        ((float4*)out)[bj * (Dc / 4) + c4] = acc;
    }
}

// ---------------------------------------------------------------------------
extern "C" void kernel_launch(void* const* d_in, const int* in_sizes, int n_in,
                              void* d_out, int out_size, void* d_ws, size_t ws_size,
                              hipStream_t stream) {
    const float* f_b = (const float*)d_in[0];
    const float* f_w = (const float*)d_in[1];
    const float* f_s = (const float*)d_in[2];
    const float* f_m = (const float*)d_in[3];
    const float* Wq  = (const float*)d_in[4];
    const float* bq  = (const float*)d_in[5];
    const float* Wk  = (const float*)d_in[6];
    const float* bk  = (const float*)d_in[7];
    float* out = (float*)d_out;

    float* ws   = (float*)d_ws;
    float* qb   = ws;                  // 8 * 512*512
    float* kb   = qb   + 8 * 512 * Dc; // 2 * 80*512
    float* f_bq = kb   + 2 * 80 * Dc;  // 512*512
    float* A_b  = f_bq + 512 * Dc;     // 512*128
    float* A_bT = A_b  + 512 * Nc;     // 512*128

    proj_gemm<<<2144, 256, 0, stream>>>(f_b, f_w, Wq, bq, Wk, bk, qb, kb);
    cross_attn_gate<<<Bc * Nc, 512, 0, stream>>>(qb, kb, f_w, f_b, f_s, f_bq);
    self_attn_scores<<<Bc * Nc, 512, 0, stream>>>(f_bq, A_b, A_bT);
    moment_final<<<dim3(Bc * Nc, 4), 256, 0, stream>>>(f_m, f_s, A_b, A_bT, f_b, out);
}

// Round 11
// 243.081 us; speedup vs baseline: 1.0131x; 1.0131x over previous
//
#include <hip/hip_runtime.h>
#include <hip/hip_bf16.h>

// B=4, N=128, L=20, D=512
#define Bc 4
#define Nc 128
#define Lc 20
#define Dc 512
#define SCALE 0.04419417382415922f   // 1/sqrt(512)
#define NL2E -1.4426950408889634f    // -log2(e)

#if __has_builtin(__builtin_amdgcn_exp2f)
#define EXP2(x) __builtin_amdgcn_exp2f(x)
#else
#define EXP2(x) __expf((x) * 0.6931471805599453f)
#endif

// ---------------------------------------------------------------------------
// Kernel 1: q/k projections. 32x32 tiles, 2x2 micro-tile, k-major LDS,
// 4-way K-split (blockIdx.z, K=128 each) + register prefetch. 1216 blocks.
// Partial outputs q[kh] / k[kh]; consumers sum the 4 parts.
// ---------------------------------------------------------------------------
__global__ __launch_bounds__(256)
void proj_gemm(const float* __restrict__ f_b, const float* __restrict__ f_w,
               const float* __restrict__ Wq, const float* __restrict__ bq,
               const float* __restrict__ Wk, const float* __restrict__ bk,
               float* __restrict__ qb, float* __restrict__ kb) {
    const int t  = threadIdx.x;
    const int tr = blockIdx.y, tc = blockIdx.x, kh = blockIdx.z;
    const int c0 = tc * 32;
    const bool isq = tr < 16;
    const float* Ain  = isq ? f_b : f_w;
    const float* W    = isq ? Wq : Wk;
    const float* bias = isq ? bq : bk;           // added only in kh==0 part
    float* C          = isq ? (qb + kh * 512 * Dc) : (kb + kh * 80 * Dc);
    const int r0    = isq ? tr * 32 : (tr - 16) * 32;
    const int nrows = isq ? 512 : 80;
    const int kbase = kh * 128;

    __shared__ __align__(16) float As[16 * 34];   // [k][row+pad]
    __shared__ __align__(16) float Bs[16 * 34];

    const int sr  = t >> 3;            // staged row 0..31
    const int sk2 = (t & 7) * 2;       // staged k pair 0..14
    const int arow = min(r0 + sr, nrows - 1);
    const int wrow = c0 + sr;

    const int ty2 = (t >> 4) * 2;      // out row pair
    const int tx2 = (t & 15) * 2;      // out col pair
    float a00 = 0.f, a01 = 0.f, a10 = 0.f, a11 = 0.f;

    const float* Aptr = Ain + arow * Dc + kbase + sk2;
    const float* Wptr = W   + wrow * Dc + kbase + sk2;
    float2 ga = *(const float2*)Aptr;
    float2 gb = *(const float2*)Wptr;

    for (int kk0 = 16; kk0 <= 128; kk0 += 16) {
        __syncthreads();
        As[sk2 * 34 + sr]       = ga.x;
        As[(sk2 + 1) * 34 + sr] = ga.y;
        Bs[sk2 * 34 + sr]       = gb.x;
        Bs[(sk2 + 1) * 34 + sr] = gb.y;
        __syncthreads();
        if (kk0 < 128) {                       // prefetch next tile
            ga = *(const float2*)(Aptr + kk0);
            gb = *(const float2*)(Wptr + kk0);
        }
#pragma unroll
        for (int kk = 0; kk < 16; kk++) {
            const float2 av = *(const float2*)&As[kk * 34 + ty2];
            const float2 bv = *(const float2*)&Bs[kk * 34 + tx2];
            a00 = fmaf(av.x, bv.x, a00); a01 = fmaf(av.x, bv.y, a01);
            a10 = fmaf(av.y, bv.x, a10); a11 = fmaf(av.y, bv.y, a11);
        }
    }
    const int orow = r0 + ty2;
    const float b0 = kh ? 0.f : bias[c0 + tx2];
    const float b1 = kh ? 0.f : bias[c0 + tx2 + 1];
    if (orow < nrows)
        *(float2*)&C[orow * Dc + c0 + tx2] = make_float2(a00 + b0, a01 + b1);
    if (orow + 1 < nrows)
        *(float2*)&C[(orow + 1) * Dc + c0 + tx2] = make_float2(a10 + b0, a11 + b1);
}

// ---------------------------------------------------------------------------
// Kernel 2: cross-attention over L=20 + sentence gate -> f_bq
// (sums the four K-split parts of q and k at load)
// ---------------------------------------------------------------------------
__global__ __launch_bounds__(256)
void cross_attn_gate(const float* __restrict__ qb, const float* __restrict__ kb,
                     const float* __restrict__ f_w, const float* __restrict__ f_b,
                     const float* __restrict__ f_s, float* __restrict__ f_bq) {
    const int bn = blockIdx.x;
    const int b  = bn >> 7;
    const int t  = threadIdx.x;
    const int lane = t & 63, wave = t >> 6;

    __shared__ __align__(16) float qs[Dc];
    __shared__ float sc[32];
    __shared__ float invs;

    {
        float2 s = make_float2(0.f, 0.f);
#pragma unroll
        for (int h = 0; h < 4; h++) {
            const float2 u = ((const float2*)(qb + h * 512 * Dc + bn * Dc))[t];
            s.x += u.x; s.y += u.y;
        }
        ((float2*)qs)[t] = s;
    }
    __syncthreads();

    const float4* q4 = (const float4*)qs;
    const float4 qa = q4[lane];
    const float4 qv = q4[lane + 64];

    for (int l = wave; l < Lc; l += 4) {
        float4 ka = make_float4(0.f, 0.f, 0.f, 0.f);
        float4 kv = make_float4(0.f, 0.f, 0.f, 0.f);
#pragma unroll
        for (int h = 0; h < 4; h++) {
            const float4* kr = (const float4*)(kb + h * 80 * Dc + (b * Lc + l) * Dc);
            const float4 u = kr[lane];
            const float4 v = kr[lane + 64];
            ka.x += u.x; ka.y += u.y; ka.z += u.z; ka.w += u.w;
            kv.x += v.x; kv.y += v.y; kv.z += v.z; kv.w += v.w;
        }
        float s = qa.x * ka.x + qa.y * ka.y + qa.z * ka.z + qa.w * ka.w
                + qv.x * kv.x + qv.y * kv.y + qv.z * kv.z + qv.w * kv.w;
#pragma unroll
        for (int d = 32; d >= 1; d >>= 1) s += __shfl_down(s, d, 64);
        if (lane == 0) sc[l] = s * SCALE;
    }
    __syncthreads();

    if (t == 0) {
        float mx = sc[0];
        for (int l = 1; l < Lc; l++) mx = fmaxf(mx, sc[l]);
        float sum = 0.f;
        for (int l = 0; l < Lc; l++) { float e = __expf(sc[l] - mx); sc[l] = e; sum += e; }
        invs = 1.0f / sum;
    }
    __syncthreads();
    const float inv = invs;

    const float2* fw2 = (const float2*)(f_w + b * Lc * Dc);
    float2 acc = make_float2(0.f, 0.f);
#pragma unroll 5
    for (int l = 0; l < Lc; l++) {
        const float2 v = fw2[l * 256 + t];
        const float w = sc[l];
        acc.x = fmaf(w, v.x, acc.x);
        acc.y = fmaf(w, v.y, acc.y);
    }
    const float2 s2 = ((const float2*)(f_s + b * Dc))[t];
    const float2 fb2 = ((const float2*)(f_b + bn * Dc))[t];
    float2 o;
    o.x = fb2.x * (acc.x * inv + s2.x);
    o.y = fb2.y * (acc.y * inv + s2.y);
    ((float2*)(f_bq + bn * Dc))[t] = o;
}

// ---------------------------------------------------------------------------
// Kernel 3: A_b / A_bT softmax rows. 512 threads (8 waves -> 4 waves/SIMD).
// ---------------------------------------------------------------------------
__global__ __launch_bounds__(512)
void self_attn_scores(const float* __restrict__ f_bq,
                      float* __restrict__ A_b, float* __restrict__ A_bT) {
    const int bn = blockIdx.x;
    const int b  = bn >> 7, n = bn & 127;
    const int t  = threadIdx.x;          // 0..511
    const int lane = t & 63, wave = t >> 6;   // 8 waves

    __shared__ __align__(16) float qrow[Dc];
    __shared__ float sc[Nc];
    __shared__ float red[Nc];

    qrow[t] = f_bq[bn * Dc + t];
    __syncthreads();

    const float4* q4 = (const float4*)qrow;
    const float4 qa = q4[lane];
    const float4 qv = q4[lane + 64];

    for (int m = wave; m < Nc; m += 8) {
        const float4* kr = (const float4*)(f_bq + (b * Nc + m) * Dc);
        const float4 va = kr[lane];
        const float4 vb = kr[lane + 64];
        float s = qa.x * va.x + qa.y * va.y + qa.z * va.z + qa.w * va.w
                + qv.x * vb.x + qv.y * vb.y + qv.z * vb.z + qv.w * vb.w;
#pragma unroll
        for (int d = 32; d >= 1; d >>= 1) s += __shfl_down(s, d, 64);
        if (lane == 0) sc[m] = s * SCALE;
    }
    __syncthreads();

    float e = 0.f, sval = 0.f;
    if (t < Nc) { sval = sc[t]; red[t] = sval; }
    __syncthreads();
    for (int st = 64; st >= 1; st >>= 1) {
        if (t < st) red[t] = fmaxf(red[t], red[t + st]);
        __syncthreads();
    }
    const float mx = red[0];
    __syncthreads();
    if (t < Nc) { e = __expf(sval - mx); red[t] = e; }
    __syncthreads();
    for (int st = 64; st >= 1; st >>= 1) {
        if (t < st) red[t] += red[t + st];
        __syncthreads();
    }
    if (t < Nc) {
        const float a = e * (1.0f / red[0]);
        A_b[bn * Nc + t] = a;
        A_bT[(b * Nc + t) * Nc + n] = a;
    }
}

// ---------------------------------------------------------------------------
// Kernel 4: fused moment reduction + self-attn apply + residual.
// grid (512, 4): blockIdx.x = (b,j), blockIdx.y = d-quarter (32 float4).
// 256 threads = 32 f4-lanes x 8 i/m-groups -> 2048 blocks = 8 blocks/CU.
// ---------------------------------------------------------------------------
__global__ __launch_bounds__(256, 8)
void moment_final(const float* __restrict__ f_m, const float* __restrict__ f_s,
                  const float* __restrict__ A_b, const float* __restrict__ A_bT,
                  const float* __restrict__ f_b, float* __restrict__ out) {
    const int bj = blockIdx.x;
    const int b  = bj >> 7, j = bj & 127;
    const int dq = blockIdx.y;         // 0..3
    const int t  = threadIdx.x;        // 0..255
    const int c  = t & 31;             // f4 lane within d-quarter
    const int g  = t >> 5;             // 0..7 i/m group

    __shared__ float w[Nc];
    __shared__ float ar[Nc];
    __shared__ __align__(16) float4 pex[7][32];

    if (t < Nc) w[t] = A_bT[bj * Nc + t];
    else        ar[t - Nc] = A_b[bj * Nc + (t - Nc)];
    __syncthreads();

    const int c4 = dq * 32 + c;        // global f4 column 0..127
    const float4 s4 = ((const float4*)(f_s + b * Dc))[c4];
    const float4 ns = make_float4(NL2E * s4.x, NL2E * s4.y, NL2E * s4.z, NL2E * s4.w);

    float4 acc = make_float4(0.f, 0.f, 0.f, 0.f);
    const float4* fm4 = (const float4*)f_m;
    int idx = ((b * Nc + g * 16) * Nc + j) * (Dc / 4) + c4;   // i-stride = 128*128 f4

#pragma unroll 4
    for (int i = 0; i < 16; i++) {
        const float4 m4 = fm4[idx];
        idx += Nc * (Dc / 4);
        const float ww = w[g * 16 + i];
        acc.x = fmaf(ww * m4.x, __builtin_amdgcn_rcpf(1.f + EXP2(m4.x * ns.x)), acc.x);
        acc.y = fmaf(ww * m4.y, __builtin_amdgcn_rcpf(1.f + EXP2(m4.y * ns.y)), acc.y);
        acc.z = fmaf(ww * m4.z, __builtin_amdgcn_rcpf(1.f + EXP2(m4.z * ns.z)), acc.z);
        acc.w = fmaf(ww * m4.w, __builtin_amdgcn_rcpf(1.f + EXP2(m4.w * ns.w)), acc.w);
    }

    const float4* fb4 = (const float4*)(f_b + b * Nc * Dc);
#pragma unroll 4
    for (int m = g * 16; m < g * 16 + 16; m++) {
        const float a = ar[m];
        const float4 v = fb4[m * (Dc / 4) + c4];
        acc.x = fmaf(a, v.x, acc.x); acc.y = fmaf(a, v.y, acc.y);
        acc.z = fmaf(a, v.z, acc.z); acc.w = fmaf(a, v.w, acc.w);
    }

    if (g != 0) pex[g - 1][c] = acc;
    __syncthreads();
    if (g == 0) {
#pragma unroll
        for (int p = 0; p < 7; p++) {
            const float4 q = pex[p][c];
            acc.x += q.x; acc.y += q.y; acc.z += q.z; acc.w += q.w;
        }
        const float4 r = fb4[j * (Dc / 4) + c4];   // residual
        acc.x += r.x; acc.y += r.y; acc.z += r.z; acc.w += r.w;
        ((float4*)out)[bj * (Dc / 4) + c4] = acc;
    }
}

// ---------------------------------------------------------------------------
extern "C" void kernel_launch(void* const* d_in, const int* in_sizes, int n_in,
                              void* d_out, int out_size, void* d_ws, size_t ws_size,
                              hipStream_t stream) {
    const float* f_b = (const float*)d_in[0];
    const float* f_w = (const float*)d_in[1];
    const float* f_s = (const float*)d_in[2];
    const float* f_m = (const float*)d_in[3];
    const float* Wq  = (const float*)d_in[4];
    const float* bq  = (const float*)d_in[5];
    const float* Wk  = (const float*)d_in[6];
    const float* bk  = (const float*)d_in[7];
    float* out = (float*)d_out;

    float* ws   = (float*)d_ws;
    float* qb   = ws;                  // 4 * 512*512
    float* kb   = qb   + 4 * 512 * Dc; // 4 * 80*512
    float* f_bq = kb   + 4 * 80 * Dc;  // 512*512
    float* A_b  = f_bq + 512 * Dc;     // 512*128
    float* A_bT = A_b  + 512 * Nc;     // 512*128

    proj_gemm<<<dim3(16, 19, 4), 256, 0, stream>>>(f_b, f_w, Wq, bq, Wk, bk, qb, kb);
    cross_attn_gate<<<Bc * Nc, 256, 0, stream>>>(qb, kb, f_w, f_b, f_s, f_bq);
    self_attn_scores<<<Bc * Nc, 512, 0, stream>>>(f_bq, A_b, A_bT);
    moment_final<<<dim3(Bc * Nc, 4), 256, 0, stream>>>(f_m, f_s, A_b, A_bT, f_b, out);
}